// Round 3
// baseline (483.596 us; speedup 1.0000x reference)
//
#include <hip/hip_runtime.h>

#define N_ 65536
#define D_ 768
#define L_ 100
#define B_ 8192
#define NTILES 6   // D_/128 column tiles in gemm_pooled

typedef __attribute__((ext_vector_type(8))) short short8;
typedef __attribute__((ext_vector_type(4))) float floatx4;

__device__ __forceinline__ unsigned short f2bf(float f) {
    unsigned int u = __float_as_uint(f);
    u += 0x7fff + ((u >> 16) & 1);   // RNE
    return (unsigned short)(u >> 16);
}
__device__ __forceinline__ float bf2f(unsigned short u) {
    return __uint_as_float(((unsigned int)u) << 16);
}

// async global->LDS, 16B per lane; lds dest is wave-uniform base + lane*16
__device__ __forceinline__ void gload16(const unsigned short* g, unsigned short* l) {
    __builtin_amdgcn_global_load_lds(
        (const __attribute__((address_space(1))) void*)g,
        (__attribute__((address_space(3))) void*)l, 16, 0, 0);
}

// ---- convert h_cls f32 -> bf16, 8 elems/thread ------------------------------
__global__ __launch_bounds__(256) void conv_h_kernel(
    const float* __restrict__ src, unsigned short* __restrict__ dst)
{
    int t = blockIdx.x * 256 + threadIdx.x;      // N_*D_/8 threads exactly
    float4 a = ((const float4*)src)[2 * t];
    float4 b = ((const float4*)src)[2 * t + 1];
    uint4 o;
    o.x = (unsigned)f2bf(a.x) | ((unsigned)f2bf(a.y) << 16);
    o.y = (unsigned)f2bf(a.z) | ((unsigned)f2bf(a.w) << 16);
    o.z = (unsigned)f2bf(b.x) | ((unsigned)f2bf(b.y) << 16);
    o.w = (unsigned)f2bf(b.z) | ((unsigned)f2bf(b.w) << 16);
    ((uint4*)dst)[t] = o;
}

// ---- prep: Wt (transpose W_fc), Wct (transpose+pad W_cls), zero logit -------
__global__ __launch_bounds__(256) void prep_kernel(
    const float* __restrict__ Wfc, unsigned short* __restrict__ Wt,
    const float* __restrict__ Wcls, unsigned short* __restrict__ Wct,
    float* __restrict__ logit)
{
    int t = blockIdx.x * 256 + threadIdx.x;
    if (t < D_ * D_) {
        int n = t / D_, k = t % D_;
        Wt[t] = f2bf(Wfc[k * D_ + n]);
    } else if (t < D_ * D_ + 128 * D_) {
        int u = t - D_ * D_;
        int n = u / D_, k = u % D_;
        Wct[u] = (n < L_) ? f2bf(Wcls[k * L_ + n]) : (unsigned short)0;
    } else {
        int u = t - D_ * D_ - 128 * D_;
        if (u < N_) logit[u] = 0.f;
    }
}

// ---- pooled = h @ W_fc + b_fc, fused logit partials (m97 + XCD swizzle) -----
__global__ __launch_bounds__(256) void gemm_pooled(
    const unsigned short* __restrict__ A,   // h bf16 [N][768]
    const unsigned short* __restrict__ Bt,  // Wt bf16 [768(n)][768(k)]
    const float* __restrict__ bias,         // b_fc
    const float* __restrict__ att,          // att_weight [100][768] f32
    const int* __restrict__ query,          // [N]
    unsigned short* __restrict__ P,         // pooled bf16 [N][768]
    float* __restrict__ logit)              // [N] f32, pre-zeroed, atomicAdd
{
    __shared__ __align__(16) unsigned short As[128 * 32];  // [row][k] 64B rows, NO pad
    __shared__ __align__(16) unsigned short Bs[128 * 32];
    const int tid  = threadIdx.x;
    const int lane = tid & 63;
    const int wave = tid >> 6;
    const int l15  = lane & 15;
    const int quad = lane >> 4;
    const int wm   = wave >> 1, wn = wave & 1;

    // XCD-aware swizzle: the NTILES col-blocks of one row-tile stay on one XCD
    const int bid  = blockIdx.x;          // 3072 blocks
    const int xcd  = bid & 7;
    const int j    = bid >> 3;            // 0..383
    const int colt = j % NTILES;
    const int rowt = xcd + (j / NTILES) * 8;
    const size_t mBase = (size_t)rowt * 128;
    const size_t nBase = (size_t)colt * 128;

    const int c0 = wave * 128 + lane;
    const int c1 = c0 + 64;
    const int r0 = c0 >> 2, s0 = (c0 & 3) * 8;
    const int r1 = c1 >> 2, s1 = (c1 & 3) * 8;
    unsigned short* ldsA0 = As + wave * 1024;
    unsigned short* ldsA1 = As + wave * 1024 + 512;
    unsigned short* ldsB0 = Bs + wave * 1024;
    unsigned short* ldsB1 = Bs + wave * 1024 + 512;
    const unsigned short* gA0 = A  + (mBase + r0) * D_ + s0;
    const unsigned short* gA1 = A  + (mBase + r1) * D_ + s1;
    const unsigned short* gB0 = Bt + (nBase + r0) * D_ + s0;
    const unsigned short* gB1 = Bt + (nBase + r1) * D_ + s1;

    floatx4 acc[4][4];
#pragma unroll
    for (int mi = 0; mi < 4; ++mi)
#pragma unroll
        for (int ni = 0; ni < 4; ++ni) acc[mi][ni] = (floatx4){0.f, 0.f, 0.f, 0.f};

    for (int k0 = 0; k0 < D_; k0 += 32) {
        __syncthreads();
        gload16(gA0 + k0, ldsA0);
        gload16(gA1 + k0, ldsA1);
        gload16(gB0 + k0, ldsB0);
        gload16(gB1 + k0, ldsB1);
        __syncthreads();
        short8 af[4], bfr[4];
#pragma unroll
        for (int mi = 0; mi < 4; ++mi)
            af[mi] = *(const short8*)&As[(wm * 64 + mi * 16 + l15) * 32 + quad * 8];
#pragma unroll
        for (int ni = 0; ni < 4; ++ni)
            bfr[ni] = *(const short8*)&Bs[(wn * 64 + ni * 16 + l15) * 32 + quad * 8];
#pragma unroll
        for (int mi = 0; mi < 4; ++mi)
#pragma unroll
            for (int ni = 0; ni < 4; ++ni)
                acc[mi][ni] = __builtin_amdgcn_mfma_f32_16x16x32_bf16(
                    af[mi], bfr[ni], acc[mi][ni], 0, 0, 0);
    }
    // add bias into acc (pooled value in f32)
    float bv[4];
#pragma unroll
    for (int ni = 0; ni < 4; ++ni) bv[ni] = bias[nBase + wn * 64 + ni * 16 + l15];
#pragma unroll
    for (int mi = 0; mi < 4; ++mi)
#pragma unroll
        for (int ni = 0; ni < 4; ++ni)
#pragma unroll
            for (int r = 0; r < 4; ++r) acc[mi][ni][r] += bv[ni];

    // store P (C/D: col = lane&15, row = quad*4 + reg)
#pragma unroll
    for (int ni = 0; ni < 4; ++ni) {
        int col = (int)nBase + wn * 64 + ni * 16 + l15;
#pragma unroll
        for (int mi = 0; mi < 4; ++mi)
#pragma unroll
            for (int r = 0; r < 4; ++r) {
                size_t row = mBase + wm * 64 + mi * 16 + quad * 4 + r;
                P[row * D_ + col] = f2bf(acc[mi][ni][r]);
            }
    }

    // fused logit partial: p(row) = sum_col att[query[row]][col] * pooled
#pragma unroll
    for (int mi = 0; mi < 4; ++mi) {
#pragma unroll
        for (int r = 0; r < 4; ++r) {
            int row = (int)mBase + wm * 64 + mi * 16 + quad * 4 + r;
            int q = query[row];
            const float* aq = att + (size_t)q * D_;
            float p = 0.f;
#pragma unroll
            for (int ni = 0; ni < 4; ++ni) {
                int col = (int)nBase + wn * 64 + ni * 16 + l15;
                p += aq[col] * acc[mi][ni][r];
            }
#pragma unroll
            for (int off = 8; off > 0; off >>= 1) p += __shfl_xor(p, off, 64);
            if (l15 == 0) atomicAdd(logit + row, p);
        }
    }
}

// ---- logits = bag_repre(bf16) @ Wct^T + b_cls  (m97 body, N padded 128) -----
__global__ __launch_bounds__(256) void gemm_cls(
    const unsigned short* __restrict__ A,   // repre bf16 [B_][768]
    const unsigned short* __restrict__ Bt,  // Wct bf16 [128][768]
    const float* __restrict__ bias,         // b_cls [100]
    float* __restrict__ out)                // [B_][100] f32
{
    __shared__ __align__(16) unsigned short As[128 * 32];
    __shared__ __align__(16) unsigned short Bs[128 * 32];
    const int tid  = threadIdx.x;
    const int lane = tid & 63;
    const int wave = tid >> 6;
    const int l15  = lane & 15;
    const int quad = lane >> 4;
    const int wm   = wave >> 1, wn = wave & 1;
    const size_t mBase = (size_t)blockIdx.y * 128;

    const int c0 = wave * 128 + lane;
    const int c1 = c0 + 64;
    const int r0 = c0 >> 2, s0 = (c0 & 3) * 8;
    const int r1 = c1 >> 2, s1 = (c1 & 3) * 8;
    unsigned short* ldsA0 = As + wave * 1024;
    unsigned short* ldsA1 = As + wave * 1024 + 512;
    unsigned short* ldsB0 = Bs + wave * 1024;
    unsigned short* ldsB1 = Bs + wave * 1024 + 512;
    const unsigned short* gA0 = A  + (mBase + r0) * D_ + s0;
    const unsigned short* gA1 = A  + (mBase + r1) * D_ + s1;
    const unsigned short* gB0 = Bt + (size_t)r0 * D_ + s0;
    const unsigned short* gB1 = Bt + (size_t)r1 * D_ + s1;

    floatx4 acc[4][4];
#pragma unroll
    for (int mi = 0; mi < 4; ++mi)
#pragma unroll
        for (int ni = 0; ni < 4; ++ni) acc[mi][ni] = (floatx4){0.f, 0.f, 0.f, 0.f};

    for (int k0 = 0; k0 < D_; k0 += 32) {
        __syncthreads();
        gload16(gA0 + k0, ldsA0);
        gload16(gA1 + k0, ldsA1);
        gload16(gB0 + k0, ldsB0);
        gload16(gB1 + k0, ldsB1);
        __syncthreads();
        short8 af[4], bfr[4];
#pragma unroll
        for (int mi = 0; mi < 4; ++mi)
            af[mi] = *(const short8*)&As[(wm * 64 + mi * 16 + l15) * 32 + quad * 8];
#pragma unroll
        for (int ni = 0; ni < 4; ++ni)
            bfr[ni] = *(const short8*)&Bs[(wn * 64 + ni * 16 + l15) * 32 + quad * 8];
#pragma unroll
        for (int mi = 0; mi < 4; ++mi)
#pragma unroll
            for (int ni = 0; ni < 4; ++ni)
                acc[mi][ni] = __builtin_amdgcn_mfma_f32_16x16x32_bf16(
                    af[mi], bfr[ni], acc[mi][ni], 0, 0, 0);
    }
#pragma unroll
    for (int ni = 0; ni < 4; ++ni) {
        int col = wn * 64 + ni * 16 + l15;
        if (col < L_) {
            float bvv = bias[col];
#pragma unroll
            for (int mi = 0; mi < 4; ++mi)
#pragma unroll
                for (int r = 0; r < 4; ++r) {
                    size_t row = mBase + wm * 64 + mi * 16 + quad * 4 + r;
                    out[row * L_ + col] = acc[mi][ni][r] + bvv;
                }
        }
    }
}

__device__ __forceinline__ int lower_bound_seg(const int* __restrict__ seg, int key) {
    int lo = 0, hi = N_;
    while (lo < hi) {
        int mid = (lo + hi) >> 1;
        if (seg[mid] < key) lo = mid + 1; else hi = mid;
    }
    return lo;
}

// ---- per-bag softmax + weighted sum: one wave per bag, inline offsets -------
__global__ __launch_bounds__(256) void bag_kernel(
    const unsigned short* __restrict__ P, const float* __restrict__ logit,
    const int* __restrict__ seg, unsigned short* __restrict__ R)
{
    int b    = blockIdx.x * 4 + (threadIdx.x >> 6);
    int lane = threadIdx.x & 63;
    int s = lower_bound_seg(seg, b);
    int e = lower_bound_seg(seg, b + 1);

    float m = -INFINITY;
    for (int i = s + lane; i < e; i += 64) m = fmaxf(m, logit[i]);
#pragma unroll
    for (int off = 32; off > 0; off >>= 1) m = fmaxf(m, __shfl_xor(m, off, 64));

    float z = 0.f;
    for (int i = s + lane; i < e; i += 64) z += expf(logit[i] - m);
#pragma unroll
    for (int off = 32; off > 0; off >>= 1) z += __shfl_xor(z, off, 64);
    float invz = (e > s) ? 1.f / z : 0.f;

    float acc[3][4];
#pragma unroll
    for (int jj = 0; jj < 3; ++jj)
#pragma unroll
        for (int c = 0; c < 4; ++c) acc[jj][c] = 0.f;

    for (int i = s; i < e; ++i) {
        float w = expf(logit[i] - m) * invz;   // uniform across wave
        const ushort4* row = (const ushort4*)(P + (size_t)i * D_);
#pragma unroll
        for (int jj = 0; jj < 3; ++jj) {
            ushort4 v = row[lane + jj * 64];
            acc[jj][0] += w * bf2f(v.x);
            acc[jj][1] += w * bf2f(v.y);
            acc[jj][2] += w * bf2f(v.z);
            acc[jj][3] += w * bf2f(v.w);
        }
    }
    ushort4* o = (ushort4*)(R + (size_t)b * D_);
#pragma unroll
    for (int jj = 0; jj < 3; ++jj) {
        ushort4 v;
        v.x = f2bf(acc[jj][0]); v.y = f2bf(acc[jj][1]);
        v.z = f2bf(acc[jj][2]); v.w = f2bf(acc[jj][3]);
        o[lane + jj * 64] = v;
    }
}

extern "C" void kernel_launch(void* const* d_in, const int* in_sizes, int n_in,
                              void* d_out, int out_size, void* d_ws, size_t ws_size,
                              hipStream_t stream) {
    const float* h    = (const float*)d_in[0];
    const float* Wfc  = (const float*)d_in[1];
    const float* bfc  = (const float*)d_in[2];
    const float* att  = (const float*)d_in[3];
    const float* Wcls = (const float*)d_in[4];
    const float* bcls = (const float*)d_in[5];
    const int*   query= (const int*)d_in[6];
    const int*   seg  = (const int*)d_in[7];
    float* out = (float*)d_out;

    char* w = (char*)d_ws;
    unsigned short* h_bf   = (unsigned short*)w;  w += (size_t)N_ * D_ * 2;
    unsigned short* Wt     = (unsigned short*)w;  w += (size_t)D_ * D_ * 2;
    unsigned short* Wct    = (unsigned short*)w;  w += (size_t)128 * D_ * 2;
    unsigned short* pooled = (unsigned short*)w;  w += (size_t)N_ * D_ * 2;
    float* logit           = (float*)w;           w += (size_t)N_ * 4;
    unsigned short* repre  = (unsigned short*)w;  // B_*D_*2

    conv_h_kernel<<<N_ * D_ / 8 / 256, 256, 0, stream>>>(h, h_bf);
    prep_kernel  <<<(D_ * D_ + 128 * D_ + N_ + 255) / 256, 256, 0, stream>>>(
                     Wfc, Wt, Wcls, Wct, logit);
    gemm_pooled  <<<NTILES * (N_ / 128), 256, 0, stream>>>(
                     h_bf, Wt, bfc, att, query, pooled, logit);
    bag_kernel   <<<B_ / 4, 256, 0, stream>>>(pooled, logit, seg, repre);
    gemm_cls     <<<dim3(1, B_ / 128), 256, 0, stream>>>(repre, Wct, bcls, out);
}

// Round 4
// 463.261 us; speedup vs baseline: 1.0439x; 1.0439x over previous
//
#include <hip/hip_runtime.h>

#define N_ 65536
#define D_ 768
#define L_ 100
#define B_ 8192
#define NTILES 6     // D_/128 column tiles in gemm_pooled
#define MAXBAG 64    // per-wave logit scratch (bags are Poisson(8); max ~25)

typedef __attribute__((ext_vector_type(8))) short short8;
typedef __attribute__((ext_vector_type(4))) float floatx4;

__device__ __forceinline__ unsigned short f2bf(float f) {
    unsigned int u = __float_as_uint(f);
    u += 0x7fff + ((u >> 16) & 1);   // RNE
    return (unsigned short)(u >> 16);
}
__device__ __forceinline__ float bf2f(unsigned short u) {
    return __uint_as_float(((unsigned int)u) << 16);
}

// async global->LDS, 16B per lane; lds dest is wave-uniform base + lane*16
__device__ __forceinline__ void gload16(const unsigned short* g, unsigned short* l) {
    __builtin_amdgcn_global_load_lds(
        (const __attribute__((address_space(1))) void*)g,
        (__attribute__((address_space(3))) void*)l, 16, 0, 0);
}

// ---- prep_all: conv h->bf16 | transpose W_fc | transpose+pad W_cls ----------
#define CONVH_BLK (N_ * D_ / 8 / 256)          // 24576
#define WT_BLK    ((D_ * D_ + 255) / 256)      // 2304
#define WCT_BLK   ((128 * D_ + 255) / 256)     // 384
__global__ __launch_bounds__(256) void prep_all(
    const float* __restrict__ h, unsigned short* __restrict__ h_bf,
    const float* __restrict__ Wfc, unsigned short* __restrict__ Wt,
    const float* __restrict__ Wcls, unsigned short* __restrict__ Wct)
{
    int bid = blockIdx.x;
    if (bid < CONVH_BLK) {
        int t = bid * 256 + threadIdx.x;
        float4 a = ((const float4*)h)[2 * t];
        float4 b = ((const float4*)h)[2 * t + 1];
        uint4 o;
        o.x = (unsigned)f2bf(a.x) | ((unsigned)f2bf(a.y) << 16);
        o.y = (unsigned)f2bf(a.z) | ((unsigned)f2bf(a.w) << 16);
        o.z = (unsigned)f2bf(b.x) | ((unsigned)f2bf(b.y) << 16);
        o.w = (unsigned)f2bf(b.z) | ((unsigned)f2bf(b.w) << 16);
        ((uint4*)h_bf)[t] = o;
    } else if (bid < CONVH_BLK + WT_BLK) {
        int t = (bid - CONVH_BLK) * 256 + threadIdx.x;
        if (t < D_ * D_) {
            int n = t / D_, k = t % D_;
            Wt[t] = f2bf(Wfc[k * D_ + n]);
        }
    } else {
        int t = (bid - CONVH_BLK - WT_BLK) * 256 + threadIdx.x;
        if (t < 128 * D_) {
            int n = t / D_, k = t % D_;
            Wct[t] = (n < L_) ? f2bf(Wcls[k * L_ + n]) : (unsigned short)0;
        }
    }
}

// ---- pooled = h @ W_fc + b_fc  (BK=64, XCD swizzle, global_load_lds) --------
__global__ __launch_bounds__(256) void gemm_pooled(
    const unsigned short* __restrict__ A,   // h bf16 [N][768]
    const unsigned short* __restrict__ Bt,  // Wt bf16 [768(n)][768(k)]
    const float* __restrict__ bias,         // b_fc
    unsigned short* __restrict__ P)         // pooled bf16 [N][768]
{
    // two [128][32] panels per matrix (panel p = k-sub p*32) -> 16KB each
    __shared__ __align__(16) unsigned short As[8192];
    __shared__ __align__(16) unsigned short Bs[8192];
    const int tid  = threadIdx.x;
    const int lane = tid & 63;
    const int wave = tid >> 6;
    const int l15  = lane & 15;
    const int quad = lane >> 4;
    const int wm   = wave >> 1, wn = wave & 1;

    // XCD-aware swizzle: a row-tile's NTILES col-blocks stay on one XCD
    const int bid  = blockIdx.x;          // 3072 blocks
    const int xcd  = bid & 7;
    const int j    = bid >> 3;
    const int colt = j % NTILES;
    const int rowt = xcd + (j / NTILES) * 8;
    const size_t mBase = (size_t)rowt * 128;
    const size_t nBase = (size_t)colt * 128;

    // staging: 1024 chunks of 16B per matrix per iter; 4 issues per wave
    const unsigned short* gA[4];
    const unsigned short* gB[4];
    unsigned short* lA[4];
    unsigned short* lB[4];
#pragma unroll
    for (int i = 0; i < 4; ++i) {
        int cbase = wave * 64 + i * 256;
        int c  = cbase + lane;
        int p  = c >> 9;                 // panel (k-sub *32)
        int r  = (c & 511) >> 2;         // row 0..127
        int q8 = (c & 3) * 8;            // col offset within panel
        gA[i] = A  + (mBase + r) * D_ + p * 32 + q8;
        gB[i] = Bt + (nBase + r) * D_ + p * 32 + q8;
        lA[i] = As + cbase * 8;
        lB[i] = Bs + cbase * 8;
    }

    floatx4 acc[4][4];
#pragma unroll
    for (int mi = 0; mi < 4; ++mi)
#pragma unroll
        for (int ni = 0; ni < 4; ++ni) acc[mi][ni] = (floatx4){0.f, 0.f, 0.f, 0.f};

    for (int k0 = 0; k0 < D_; k0 += 64) {
        __syncthreads();
#pragma unroll
        for (int i = 0; i < 4; ++i) {
            gload16(gA[i] + k0, lA[i]);
            gload16(gB[i] + k0, lB[i]);
        }
        __syncthreads();
#pragma unroll
        for (int h = 0; h < 2; ++h) {
            short8 af[4], bfr[4];
#pragma unroll
            for (int mi = 0; mi < 4; ++mi)
                af[mi] = *(const short8*)&As[h * 4096 + (wm * 64 + mi * 16 + l15) * 32 + quad * 8];
#pragma unroll
            for (int ni = 0; ni < 4; ++ni)
                bfr[ni] = *(const short8*)&Bs[h * 4096 + (wn * 64 + ni * 16 + l15) * 32 + quad * 8];
#pragma unroll
            for (int mi = 0; mi < 4; ++mi)
#pragma unroll
                for (int ni = 0; ni < 4; ++ni)
                    acc[mi][ni] = __builtin_amdgcn_mfma_f32_16x16x32_bf16(
                        af[mi], bfr[ni], acc[mi][ni], 0, 0, 0);
        }
    }
    // C/D: col = lane&15, row = quad*4 + reg
#pragma unroll
    for (int ni = 0; ni < 4; ++ni) {
        int col = (int)nBase + wn * 64 + ni * 16 + l15;
        float bv = bias[col];
#pragma unroll
        for (int mi = 0; mi < 4; ++mi)
#pragma unroll
            for (int r = 0; r < 4; ++r) {
                size_t row = mBase + wm * 64 + mi * 16 + quad * 4 + r;
                P[row * D_ + col] = f2bf(acc[mi][ni][r] + bv);
            }
    }
}

// ---- logits = bag_repre(bf16) @ Wct^T + b_cls -------------------------------
__global__ __launch_bounds__(256) void gemm_cls(
    const unsigned short* __restrict__ A,   // repre bf16 [B_][768]
    const unsigned short* __restrict__ Bt,  // Wct bf16 [128][768]
    const float* __restrict__ bias,         // b_cls [100]
    float* __restrict__ out)                // [B_][100] f32
{
    __shared__ __align__(16) unsigned short As[128 * 32];
    __shared__ __align__(16) unsigned short Bs[128 * 32];
    const int tid  = threadIdx.x;
    const int lane = tid & 63;
    const int wave = tid >> 6;
    const int l15  = lane & 15;
    const int quad = lane >> 4;
    const int wm   = wave >> 1, wn = wave & 1;
    const size_t mBase = (size_t)blockIdx.x * 128;

    const int c0 = wave * 128 + lane;
    const int c1 = c0 + 64;
    const int r0 = c0 >> 2, s0 = (c0 & 3) * 8;
    const int r1 = c1 >> 2, s1 = (c1 & 3) * 8;
    unsigned short* ldsA0 = As + wave * 1024;
    unsigned short* ldsA1 = As + wave * 1024 + 512;
    unsigned short* ldsB0 = Bs + wave * 1024;
    unsigned short* ldsB1 = Bs + wave * 1024 + 512;
    const unsigned short* gA0 = A  + (mBase + r0) * D_ + s0;
    const unsigned short* gA1 = A  + (mBase + r1) * D_ + s1;
    const unsigned short* gB0 = Bt + (size_t)r0 * D_ + s0;
    const unsigned short* gB1 = Bt + (size_t)r1 * D_ + s1;

    floatx4 acc[4][4];
#pragma unroll
    for (int mi = 0; mi < 4; ++mi)
#pragma unroll
        for (int ni = 0; ni < 4; ++ni) acc[mi][ni] = (floatx4){0.f, 0.f, 0.f, 0.f};

    for (int k0 = 0; k0 < D_; k0 += 32) {
        __syncthreads();
        gload16(gA0 + k0, ldsA0);
        gload16(gA1 + k0, ldsA1);
        gload16(gB0 + k0, ldsB0);
        gload16(gB1 + k0, ldsB1);
        __syncthreads();
        short8 af[4], bfr[4];
#pragma unroll
        for (int mi = 0; mi < 4; ++mi)
            af[mi] = *(const short8*)&As[(wm * 64 + mi * 16 + l15) * 32 + quad * 8];
#pragma unroll
        for (int ni = 0; ni < 4; ++ni)
            bfr[ni] = *(const short8*)&Bs[(wn * 64 + ni * 16 + l15) * 32 + quad * 8];
#pragma unroll
        for (int mi = 0; mi < 4; ++mi)
#pragma unroll
            for (int ni = 0; ni < 4; ++ni)
                acc[mi][ni] = __builtin_amdgcn_mfma_f32_16x16x32_bf16(
                    af[mi], bfr[ni], acc[mi][ni], 0, 0, 0);
    }
#pragma unroll
    for (int ni = 0; ni < 4; ++ni) {
        int col = wn * 64 + ni * 16 + l15;
        if (col < L_) {
            float bvv = bias[col];
#pragma unroll
            for (int mi = 0; mi < 4; ++mi)
#pragma unroll
                for (int r = 0; r < 4; ++r) {
                    size_t row = mBase + wm * 64 + mi * 16 + quad * 4 + r;
                    out[row * L_ + col] = acc[mi][ni][r] + bvv;
                }
        }
    }
}

__device__ __forceinline__ int lower_bound_seg(const int* __restrict__ seg, int key) {
    int lo = 0, hi = N_;
    while (lo < hi) {
        int mid = (lo + hi) >> 1;
        if (seg[mid] < key) lo = mid + 1; else hi = mid;
    }
    return lo;
}

// full-wave dot of pooled row i with att[q]; every lane returns the dot
__device__ __forceinline__ float row_logit(
    const unsigned short* __restrict__ P, const float* __restrict__ att,
    int i, int q, int lane)
{
    const ushort4* pr = (const ushort4*)(P + (size_t)i * D_);
    const float4*  ar = (const float4*)(att + (size_t)q * D_);
    float d = 0.f;
#pragma unroll
    for (int jj = 0; jj < 3; ++jj) {
        ushort4 v = pr[lane + jj * 64];
        float4  a = ar[lane + jj * 64];
        d += bf2f(v.x) * a.x + bf2f(v.y) * a.y + bf2f(v.z) * a.z + bf2f(v.w) * a.w;
    }
#pragma unroll
    for (int off = 32; off > 0; off >>= 1) d += __shfl_xor(d, off, 64);
    return d;   // identical on all 64 lanes
}

// ---- per-bag: logits + softmax + weighted sum, one wave per bag -------------
__global__ __launch_bounds__(256) void bag_kernel(
    const unsigned short* __restrict__ P, const float* __restrict__ att,
    const int* __restrict__ query, const int* __restrict__ seg,
    unsigned short* __restrict__ R)
{
    __shared__ float scratch[4][MAXBAG];
    int wv   = threadIdx.x >> 6;
    int b    = blockIdx.x * 4 + wv;
    int lane = threadIdx.x & 63;
    int s = lower_bound_seg(seg, b);
    int e = lower_bound_seg(seg, b + 1);
    int cnt = e - s;

    // pass 1: per-row logits (cached in per-wave LDS), running max
    float m = -INFINITY;
    for (int j = 0; j < cnt; ++j) {
        float d = row_logit(P, att, s + j, query[s + j], lane);
        if (j < MAXBAG && lane == 0) scratch[wv][j] = d;
        m = fmaxf(m, d);
    }
    // pass 2: z (all lanes hold full dots -> no reduction needed)
    float z = 0.f;
    for (int j = 0; j < cnt; ++j) {
        float d = (j < MAXBAG) ? scratch[wv][j]
                               : row_logit(P, att, s + j, query[s + j], lane);
        z += expf(d - m);
    }
    float invz = (cnt > 0) ? 1.f / z : 0.f;

    // pass 3: weighted sum of (L1-hot) pooled rows
    float acc[3][4];
#pragma unroll
    for (int jj = 0; jj < 3; ++jj)
#pragma unroll
        for (int c = 0; c < 4; ++c) acc[jj][c] = 0.f;
    for (int j = 0; j < cnt; ++j) {
        float d = (j < MAXBAG) ? scratch[wv][j]
                               : row_logit(P, att, s + j, query[s + j], lane);
        float w = expf(d - m) * invz;
        const ushort4* row = (const ushort4*)(P + (size_t)(s + j) * D_);
#pragma unroll
        for (int jj = 0; jj < 3; ++jj) {
            ushort4 v = row[lane + jj * 64];
            acc[jj][0] += w * bf2f(v.x);
            acc[jj][1] += w * bf2f(v.y);
            acc[jj][2] += w * bf2f(v.z);
            acc[jj][3] += w * bf2f(v.w);
        }
    }
    ushort4* o = (ushort4*)(R + (size_t)b * D_);
#pragma unroll
    for (int jj = 0; jj < 3; ++jj) {
        ushort4 v;
        v.x = f2bf(acc[jj][0]); v.y = f2bf(acc[jj][1]);
        v.z = f2bf(acc[jj][2]); v.w = f2bf(acc[jj][3]);
        o[lane + jj * 64] = v;
    }
}

extern "C" void kernel_launch(void* const* d_in, const int* in_sizes, int n_in,
                              void* d_out, int out_size, void* d_ws, size_t ws_size,
                              hipStream_t stream) {
    const float* h    = (const float*)d_in[0];
    const float* Wfc  = (const float*)d_in[1];
    const float* bfc  = (const float*)d_in[2];
    const float* att  = (const float*)d_in[3];
    const float* Wcls = (const float*)d_in[4];
    const float* bcls = (const float*)d_in[5];
    const int*   query= (const int*)d_in[6];
    const int*   seg  = (const int*)d_in[7];
    float* out = (float*)d_out;

    char* w = (char*)d_ws;
    unsigned short* h_bf   = (unsigned short*)w;  w += (size_t)N_ * D_ * 2;
    unsigned short* Wt     = (unsigned short*)w;  w += (size_t)D_ * D_ * 2;
    unsigned short* Wct    = (unsigned short*)w;  w += (size_t)128 * D_ * 2;
    unsigned short* pooled = (unsigned short*)w;  w += (size_t)N_ * D_ * 2;
    unsigned short* repre  = (unsigned short*)w;  // B_*D_*2

    prep_all   <<<CONVH_BLK + WT_BLK + WCT_BLK, 256, 0, stream>>>(
                   h, h_bf, Wfc, Wt, Wcls, Wct);
    gemm_pooled<<<NTILES * (N_ / 128), 256, 0, stream>>>(h_bf, Wt, bfc, pooled);
    bag_kernel <<<B_ / 4, 256, 0, stream>>>(pooled, att, query, seg, repre);
    gemm_cls   <<<B_ / 128, 256, 0, stream>>>(repre, Wct, bcls, out);
}